// Round 6
// baseline (207.413 us; speedup 1.0000x reference)
//
#include <hip/hip_runtime.h>
#include <hip/hip_bf16.h>
#include <stdint.h>

#define N 1024
#define DIM 64
#define MDIM 16
#define EH 258    // edge mlp hidden
#define EHP 264   // padded Bb row stride (elements); 528 bytes
#define CH 64
#define HH 128
#define PRE_ROWS 8

typedef __bf16 bf16x8 __attribute__((ext_vector_type(8)));
typedef float f32x4 __attribute__((ext_vector_type(4)));
typedef float f32x2 __attribute__((ext_vector_type(2)));
typedef uint32_t u32x4 __attribute__((ext_vector_type(4)));
union B8 { uint32_t u[4]; bf16x8 v; };

__device__ __forceinline__ uint32_t cvtpk(float lo, float hi) {
  uint32_t r;
  asm("v_cvt_pk_bf16_f32 %0, %1, %2" : "=v"(r) : "v"(lo), "v"(hi));
  return r;
}
__device__ __forceinline__ f32x2 pk_add(f32x2 a, f32x2 b) {
  f32x2 r;
  asm("v_pk_add_f32 %0, %1, %2" : "=v"(r) : "v"(a), "v"(b));
  return r;
}
__device__ __forceinline__ f32x2 pk_fma(f32x2 a, f32x2 b, f32x2 c) {
  f32x2 r;
  asm("v_pk_fma_f32 %0, %1, %2, %3" : "=v"(r) : "v"(a), "v"(b), "v"(c));
  return r;
}
__device__ __forceinline__ float bflo(uint32_t u) { return __uint_as_float(u << 16); }
__device__ __forceinline__ float bfhi(uint32_t u) { return __uint_as_float(u & 0xffff0000u); }

// A[i][k] = feats[i] @ eW1[0:64,k] + eb1[k]   (f32, stride EH)
// Bb[j][k] = feats[j] @ eW1[64:128,k]         (bf16, row-major, stride EHP)
__global__ __launch_bounds__(256) void eg_pre(
    const float* __restrict__ feats, const float* __restrict__ eW1,
    const float* __restrict__ eb1,
    float* __restrict__ A, __hip_bfloat16* __restrict__ Bb)
{
  __shared__ float sf[PRE_ROWS][DIM];
  int ib = blockIdx.x, t = threadIdx.x;
  for (int q = t; q < PRE_ROWS * DIM; q += 256)
    sf[q >> 6][q & 63] = feats[ib * PRE_ROWS * DIM + q];
  __syncthreads();
  for (int k = t; k < EH; k += 256) {
    float bias = eb1[k];
    float a[PRE_ROWS], bv[PRE_ROWS];
#pragma unroll
    for (int ii = 0; ii < PRE_ROWS; ++ii) { a[ii] = bias; bv[ii] = 0.f; }
#pragma unroll 4
    for (int d = 0; d < DIM; ++d) {
      float wt = eW1[d * EH + k];
      float wb = eW1[(DIM + d) * EH + k];
#pragma unroll
      for (int ii = 0; ii < PRE_ROWS; ++ii) {
        a[ii]  = fmaf(sf[ii][d], wt, a[ii]);
        bv[ii] = fmaf(sf[ii][d], wb, bv[ii]);
      }
    }
#pragma unroll
    for (int ii = 0; ii < PRE_ROWS; ++ii) {
      A[(ib * PRE_ROWS + ii) * EH + k] = a[ii];
      Bb[(ib * PRE_ROWS + ii) * EHP + k] = __float2bfloat16(bv[ii]);
    }
  }
}

__global__ __launch_bounds__(256, 4) void eg_main(
    const float* __restrict__ feats, const float* __restrict__ coors,
    const float* __restrict__ eW1, const float* __restrict__ eW2,
    const float* __restrict__ eb2, const float* __restrict__ cW1,
    const float* __restrict__ cb1, const float* __restrict__ cW2,
    const float* __restrict__ cb2, const float* __restrict__ hW1,
    const float* __restrict__ hb1, const float* __restrict__ hW2,
    const float* __restrict__ hb2,
    const float* __restrict__ A, const __hip_bfloat16* __restrict__ Bb,
    float* __restrict__ out)
{
  __shared__ __align__(16) float sA[EHP];
  __shared__ __align__(16) float sW3[EHP];
  __shared__ float sEW2p[EH * 17];                  // eW2 [k][c], stride-17 pad
  __shared__ __align__(16) float4 sRel4[N];         // {rx,ry,rz,dist}
  __shared__ __align__(16) float sCB1[CH];
  __shared__ __align__(16) float sCW2[CH];
  __shared__ float sEB2[MDIM], sFeat[DIM];
  __shared__ struct { float redm[4][16]; float redc[4][3]; float mi[MDIM]; float hid[HH]; } sE;

  const int i = blockIdx.x, t = threadIdx.x;
  const int lane = t & 63, wv = t >> 6;
  const int r16 = lane & 15, g = lane >> 4;

  // ---- cooperative staging ----
  for (int q = t; q < EH * MDIM; q += 256) sEW2p[(q >> 4) * 17 + (q & 15)] = eW2[q];
  for (int q = t; q < EH; q += 256) { sA[q] = A[i * EH + q]; sW3[q] = eW1[128 * EH + q]; }
  if (t < CH)   { sCB1[t] = cb1[t]; sCW2[t] = cW2[t]; }
  if (t < MDIM) sEB2[t] = eb2[t];
  if (t < DIM)  sFeat[t] = feats[i * DIM + t];
  {
    float cx = coors[i * 3], cy = coors[i * 3 + 1], cz = coors[i * 3 + 2];
    const float4* c4 = (const float4*)coors;
    float4 ca = c4[t * 3 + 0], cb = c4[t * 3 + 1], cc = c4[t * 3 + 2];
    float jx[4] = {ca.x, ca.w, cb.z, cc.y};
    float jy[4] = {ca.y, cb.x, cb.w, cc.z};
    float jz[4] = {ca.z, cb.y, cc.x, cc.w};
#pragma unroll
    for (int q = 0; q < 4; ++q) {
      float rx = cx - jx[q], ry = cy - jy[q], rz = cz - jz[q];
      float d = sqrtf(fmaf(rx, rx, fmaf(ry, ry, rz * rz)));
      sRel4[t * 4 + q] = make_float4(rx, ry, rz, d);
    }
  }
  // one-time scattered gather from global (L2-hot): cW1^T A-fragments, K 16->32 pad
  B8 fcw1[4];
#pragma unroll
  for (int T = 0; T < 4; ++T) {
    float cv[8];
#pragma unroll
    for (int e = 0; e < 8; ++e)
      cv[e] = (g < 2) ? cW1[(8 * g + e) * CH + 16 * T + r16] : 0.f;
    fcw1[T].u[0] = cvtpk(cv[0], cv[1]); fcw1[T].u[1] = cvtpk(cv[2], cv[3]);
    fcw1[T].u[2] = cvtpk(cv[4], cv[5]); fcw1[T].u[3] = cvtpk(cv[6], cv[7]);
  }
  float cb2v = cb2[0];
  __syncthreads();

  // ---- per-lane constants from LDS ----
  f32x4 eb2r;
#pragma unroll
  for (int r = 0; r < 4; ++r) eb2r[r] = sEB2[4 * g + r];
  float tw0[4], tw1[4];
#pragma unroll
  for (int r = 0; r < 4; ++r) {
    tw0[r] = sEW2p[256 * 17 + 4 * g + r];
    tw1[r] = sEW2p[257 * 17 + 4 * g + r];
  }
  float a256 = sA[256], a257 = sA[257], w356 = sW3[256], w357 = sW3[257];

  const f32x2* sA2 = (const f32x2*)sA;
  const f32x2* sW32 = (const f32x2*)sW3;
  const char* Bbyte = (const char*)Bb;
  const int ewb = g * 136 + r16;           // sEW2p dword base for this lane

  float macc[4] = {0.f, 0.f, 0.f, 0.f};
  float cax = 0.f, cay = 0.f, caz = 0.f;

#pragma unroll 1
  for (int p = 0; p < 2; ++p) {
    const int jb = wv * 16 + p * 512;
    float djp[8];
    f32x4 D[8];
    const char* brow[8];
#pragma unroll
    for (int tt = 0; tt < 8; ++tt) {
      djp[tt] = sRel4[jb + tt * 64 + r16].w;
      D[tt] = eb2r;
      brow[tt] = Bbyte + (size_t)((jb + tt * 64 + r16) * (EHP * 2) + g * 16);
    }

#pragma unroll
    for (int s = 0; s < 8; ++s) {
      // A/W3 pairs for this k-octet (wave-uniform per 16-lane group)
      f32x2 a2[4], w2[4];
#pragma unroll
      for (int q = 0; q < 4; ++q) {
        a2[q] = sA2[16 * s + 4 * g + q];
        w2[q] = sW32[16 * s + 4 * g + q];
      }
      // eW2^T fragment (padded LDS: worst 2-way bank alias = free)
      B8 few;
#pragma unroll
      for (int h = 0; h < 4; ++h)
        few.u[h] = cvtpk(sEW2p[ewb + s * 544 + (2 * h) * 17],
                         sEW2p[ewb + s * 544 + (2 * h + 1) * 17]);
#pragma unroll
      for (int tt = 0; tt < 8; ++tt) {
        u32x4 bq = *(const u32x4*)(brow[tt] + s * 64);
        f32x2 dd; dd[0] = djp[tt]; dd[1] = djp[tt];
        B8 hb;
#pragma unroll
        for (int q = 0; q < 4; ++q) {
          f32x2 bp; bp[0] = bflo(bq[q]); bp[1] = bfhi(bq[q]);
          f32x2 hv = pk_add(bp, a2[q]);
          hv = pk_fma(dd, w2[q], hv);
          hb.u[q] = cvtpk(fmaxf(hv[0], 0.f), fmaxf(hv[1], 0.f));
        }
        D[tt] = __builtin_amdgcn_mfma_f32_16x16x32_bf16(few.v, hb.v, D[tt], 0, 0, 0);
      }
    }

    // ---- per-tile tail (k=256,257) + coors MLP + accumulation ----
    const f32x4* cb14 = (const f32x4*)sCB1;
    const f32x4* cw24 = (const f32x4*)sCW2;
#pragma unroll
    for (int tt = 0; tt < 8; ++tt) {
      const int j = jb + tt * 64 + r16;
      float4 rl = sRel4[j];
      uint32_t bt = *(const uint32_t*)(Bbyte + (size_t)(j * (EHP * 2) + 512));
      float h6 = fmaxf(fmaf(rl.w, w356, a256 + bflo(bt)), 0.f);
      float h7 = fmaxf(fmaf(rl.w, w357, a257 + bfhi(bt)), 0.f);
#pragma unroll
      for (int r = 0; r < 4; ++r) {
        D[tt][r] = fmaf(h6, tw0[r], D[tt][r]);
        D[tt][r] = fmaf(h7, tw1[r], D[tt][r]);
        macc[r] += D[tt][r];
      }
      // redistribute m^T D-frag -> B-frag (K padded to 32, zeros for k>=16)
      uint32_t p0 = cvtpk(D[tt][0], D[tt][1]);
      uint32_t p1 = cvtpk(D[tt][2], D[tt][3]);
      int s0 = r16 + (((2 * g) & 3) << 4);
      int s1 = r16 + (((2 * g + 1) & 3) << 4);
      uint32_t b0 = (uint32_t)__shfl((int)p0, s0, 64);
      uint32_t b1 = (uint32_t)__shfl((int)p1, s0, 64);
      uint32_t b2 = (uint32_t)__shfl((int)p0, s1, 64);
      uint32_t b3 = (uint32_t)__shfl((int)p1, s1, 64);
      B8 mf;
      mf.u[0] = (g < 2) ? b0 : 0u; mf.u[1] = (g < 2) ? b1 : 0u;
      mf.u[2] = (g < 2) ? b2 : 0u; mf.u[3] = (g < 2) ? b3 : 0u;
      float wacc = 0.f;
#pragma unroll
      for (int T = 0; T < 4; ++T) {
        f32x4 cbv = cb14[4 * T + g];
        f32x4 hd = __builtin_amdgcn_mfma_f32_16x16x32_bf16(fcw1[T].v, mf.v, cbv, 0, 0, 0);
        f32x4 cwv = cw24[4 * T + g];
#pragma unroll
        for (int r = 0; r < 4; ++r)
          wacc = fmaf(fmaxf(hd[r], 0.f), cwv[r], wacc);
      }
      wacc += __shfl_xor(wacc, 16, 64);
      wacc += __shfl_xor(wacc, 32, 64);
      float w = cb2v + wacc;
      cax = fmaf(w, rl.x, cax); cay = fmaf(w, rl.y, cay); caz = fmaf(w, rl.z, caz);
    }
  }

  // ---- reductions: sum over r16 (j within wave) ----
#pragma unroll
  for (int off = 1; off < 16; off <<= 1) {
#pragma unroll
    for (int r = 0; r < 4; ++r) macc[r] += __shfl_xor(macc[r], off, 64);
    cax += __shfl_xor(cax, off, 64);
    cay += __shfl_xor(cay, off, 64);
    caz += __shfl_xor(caz, off, 64);
  }
  if (r16 == 0) {
#pragma unroll
    for (int r = 0; r < 4; ++r) sE.redm[wv][4 * g + r] = macc[r];
    if (g == 0) { sE.redc[wv][0] = cax; sE.redc[wv][1] = cay; sE.redc[wv][2] = caz; }
  }
  __syncthreads();
  if (t < MDIM)
    sE.mi[t] = sE.redm[0][t] + sE.redm[1][t] + sE.redm[2][t] + sE.redm[3][t];
  if (t >= 16 && t < 19) {
    int c = t - 16;
    out[N * DIM + i * 3 + c] = sE.redc[0][c] + sE.redc[1][c] + sE.redc[2][c] + sE.redc[3][c];
  }
  __syncthreads();

  // ---- hidden mlp: [feats(64), m_i(16)] -> 128 -> relu -> 64 ----
  if (t < HH) {
    float acc = hb1[t];
#pragma unroll 8
    for (int d = 0; d < DIM; ++d) acc = fmaf(sFeat[d], hW1[d * HH + t], acc);
#pragma unroll
    for (int d = 0; d < MDIM; ++d) acc = fmaf(sE.mi[d], hW1[(DIM + d) * HH + t], acc);
    sE.hid[t] = fmaxf(acc, 0.f);
  }
  __syncthreads();
  if (t < DIM) {
    float acc = hb2[t];
#pragma unroll 8
    for (int c = 0; c < HH; ++c) acc = fmaf(sE.hid[c], hW2[c * DIM + t], acc);
    out[i * DIM + t] = acc;
  }
}

extern "C" void kernel_launch(void* const* d_in, const int* in_sizes, int n_in,
                              void* d_out, int out_size, void* d_ws, size_t ws_size,
                              hipStream_t stream) {
  const float* feats = (const float*)d_in[0];
  const float* coors = (const float*)d_in[1];
  const float* eW1   = (const float*)d_in[2];
  const float* eb1   = (const float*)d_in[3];
  const float* eW2   = (const float*)d_in[4];
  const float* eb2   = (const float*)d_in[5];
  const float* cW1   = (const float*)d_in[6];
  const float* cb1   = (const float*)d_in[7];
  const float* cW2   = (const float*)d_in[8];
  const float* cb2   = (const float*)d_in[9];
  const float* hW1   = (const float*)d_in[10];
  const float* hb1   = (const float*)d_in[11];
  const float* hW2   = (const float*)d_in[12];
  const float* hb2   = (const float*)d_in[13];

  float* A = (float*)d_ws;                                     // 1024*258 f32
  __hip_bfloat16* Bb = (__hip_bfloat16*)((char*)d_ws + (size_t)N * EH * 4);  // 1024*264 bf16
  float* out = (float*)d_out;

  eg_pre<<<N / PRE_ROWS, 256, 0, stream>>>(feats, eW1, eb1, A, Bb);
  eg_main<<<N, 256, 0, stream>>>(feats, coors, eW1, eW2, eb2, cW1, cb1, cW2, cb2,
                                 hW1, hb1, hW2, hb2, A, Bb, out);
}

// Round 8
// 166.302 us; speedup vs baseline: 1.2472x; 1.2472x over previous
//
#include <hip/hip_runtime.h>
#include <hip/hip_bf16.h>
#include <stdint.h>

#define N 1024
#define DIM 64
#define MDIM 16
#define EH 258    // edge mlp hidden
#define EHP 264   // padded Bb row stride (elements); 528 bytes
#define CH 64
#define HH 128
#define PRE_ROWS 8

typedef __bf16 bf16x8 __attribute__((ext_vector_type(8)));
typedef float f32x4 __attribute__((ext_vector_type(4)));
typedef float f32x2 __attribute__((ext_vector_type(2)));
typedef uint32_t u32x4 __attribute__((ext_vector_type(4)));
union B8 { uint32_t u[4]; bf16x8 v; };

__device__ __forceinline__ uint32_t cvtpk(float lo, float hi) {
  uint32_t r;
  asm("v_cvt_pk_bf16_f32 %0, %1, %2" : "=v"(r) : "v"(lo), "v"(hi));
  return r;
}
__device__ __forceinline__ f32x2 pk_add(f32x2 a, f32x2 b) {
  f32x2 r;
  asm("v_pk_add_f32 %0, %1, %2" : "=v"(r) : "v"(a), "v"(b));
  return r;
}
__device__ __forceinline__ f32x2 pk_fma(f32x2 a, f32x2 b, f32x2 c) {
  f32x2 r;
  asm("v_pk_fma_f32 %0, %1, %2, %3" : "=v"(r) : "v"(a), "v"(b), "v"(c));
  return r;
}
__device__ __forceinline__ float bflo(uint32_t u) { return __uint_as_float(u << 16); }
__device__ __forceinline__ float bfhi(uint32_t u) { return __uint_as_float(u & 0xffff0000u); }

// A[i][k] = feats[i] @ eW1[0:64,k] + eb1[k]   (f32, stride EH)
// Bb[j][k] = feats[j] @ eW1[64:128,k]         (bf16, row-major, stride EHP)
__global__ __launch_bounds__(256) void eg_pre(
    const float* __restrict__ feats, const float* __restrict__ eW1,
    const float* __restrict__ eb1,
    float* __restrict__ A, __hip_bfloat16* __restrict__ Bb)
{
  __shared__ float sf[PRE_ROWS][DIM];
  int ib = blockIdx.x, t = threadIdx.x;
  for (int q = t; q < PRE_ROWS * DIM; q += 256)
    sf[q >> 6][q & 63] = feats[ib * PRE_ROWS * DIM + q];
  __syncthreads();
  for (int k = t; k < EH; k += 256) {
    float bias = eb1[k];
    float a[PRE_ROWS], bv[PRE_ROWS];
#pragma unroll
    for (int ii = 0; ii < PRE_ROWS; ++ii) { a[ii] = bias; bv[ii] = 0.f; }
#pragma unroll 4
    for (int d = 0; d < DIM; ++d) {
      float wt = eW1[d * EH + k];
      float wb = eW1[(DIM + d) * EH + k];
#pragma unroll
      for (int ii = 0; ii < PRE_ROWS; ++ii) {
        a[ii]  = fmaf(sf[ii][d], wt, a[ii]);
        bv[ii] = fmaf(sf[ii][d], wb, bv[ii]);
      }
    }
#pragma unroll
    for (int ii = 0; ii < PRE_ROWS; ++ii) {
      A[(ib * PRE_ROWS + ii) * EH + k] = a[ii];
      Bb[(ib * PRE_ROWS + ii) * EHP + k] = __float2bfloat16(bv[ii]);
    }
  }
}

// One k-step: h = relu(A + B + dist*W3) packed-f32, pack to bf16, MFMA vs eW2^T.
__device__ __forceinline__ void egc_step(
    int s, const u32x4* bq, const float* djp, f32x4* D,
    const f32x2* sA2, const f32x2* sW32, const float* sEW2p,
    int ewb, int g)
{
  f32x2 a2[4], w2[4];
#pragma unroll
  for (int q = 0; q < 4; ++q) {
    a2[q] = sA2[16 * s + 4 * g + q];
    w2[q] = sW32[16 * s + 4 * g + q];
  }
  B8 few;
#pragma unroll
  for (int h = 0; h < 4; ++h)
    few.u[h] = cvtpk(sEW2p[ewb + s * 544 + (2 * h) * 17],
                     sEW2p[ewb + s * 544 + (2 * h + 1) * 17]);
#pragma unroll
  for (int tt = 0; tt < 8; ++tt) {
    f32x2 dd; dd[0] = djp[tt]; dd[1] = djp[tt];
    B8 hb;
#pragma unroll
    for (int q = 0; q < 4; ++q) {
      f32x2 bp; bp[0] = bflo(bq[tt][q]); bp[1] = bfhi(bq[tt][q]);
      f32x2 hv = pk_add(bp, a2[q]);
      hv = pk_fma(dd, w2[q], hv);
      hb.u[q] = cvtpk(fmaxf(hv[0], 0.f), fmaxf(hv[1], 0.f));
    }
    D[tt] = __builtin_amdgcn_mfma_f32_16x16x32_bf16(few.v, hb.v, D[tt], 0, 0, 0);
  }
}

__global__ __launch_bounds__(256, 2) void eg_main(
    const float* __restrict__ feats, const float* __restrict__ coors,
    const float* __restrict__ eW1, const float* __restrict__ eW2,
    const float* __restrict__ eb2, const float* __restrict__ cW1,
    const float* __restrict__ cb1, const float* __restrict__ cW2,
    const float* __restrict__ cb2, const float* __restrict__ hW1,
    const float* __restrict__ hb1, const float* __restrict__ hW2,
    const float* __restrict__ hb2,
    const float* __restrict__ A, const __hip_bfloat16* __restrict__ Bb,
    float* __restrict__ out)
{
  __shared__ __align__(16) float sA[EHP];
  __shared__ __align__(16) float sW3[EHP];
  __shared__ float sEW2p[EH * 17];                  // eW2 [k][c], stride-17 pad
  __shared__ __align__(16) float4 sRel4[N];         // {rx,ry,rz,dist}
  __shared__ __align__(16) float sCB1[CH];
  __shared__ __align__(16) float sCW2[CH];
  __shared__ float sEB2[MDIM], sFeat[DIM];
  __shared__ struct { float redm[4][16]; float redc[4][3]; float mi[MDIM]; float hid[HH]; } sE;

  const int i = blockIdx.x, t = threadIdx.x;
  const int lane = t & 63, wv = t >> 6;
  const int r16 = lane & 15, g = lane >> 4;

  // ---- cooperative staging ----
  for (int q = t; q < EH * MDIM; q += 256) sEW2p[(q >> 4) * 17 + (q & 15)] = eW2[q];
  for (int q = t; q < EH; q += 256) { sA[q] = A[i * EH + q]; sW3[q] = eW1[128 * EH + q]; }
  if (t < CH)   { sCB1[t] = cb1[t]; sCW2[t] = cW2[t]; }
  if (t < MDIM) sEB2[t] = eb2[t];
  if (t < DIM)  sFeat[t] = feats[i * DIM + t];
  {
    float cx = coors[i * 3], cy = coors[i * 3 + 1], cz = coors[i * 3 + 2];
    const float4* c4 = (const float4*)coors;
    float4 ca = c4[t * 3 + 0], cb = c4[t * 3 + 1], cc = c4[t * 3 + 2];
    float jx[4] = {ca.x, ca.w, cb.z, cc.y};
    float jy[4] = {ca.y, cb.x, cb.w, cc.z};
    float jz[4] = {ca.z, cb.y, cc.x, cc.w};
#pragma unroll
    for (int q = 0; q < 4; ++q) {
      float rx = cx - jx[q], ry = cy - jy[q], rz = cz - jz[q];
      float d = sqrtf(fmaf(rx, rx, fmaf(ry, ry, rz * rz)));
      sRel4[t * 4 + q] = make_float4(rx, ry, rz, d);
    }
  }
  // one-time scattered gather (L2-hot): cW1^T A-fragments, K 16->32 pad
  B8 fcw1[4];
#pragma unroll
  for (int T = 0; T < 4; ++T) {
    float cv[8];
#pragma unroll
    for (int e = 0; e < 8; ++e)
      cv[e] = (g < 2) ? cW1[(8 * g + e) * CH + 16 * T + r16] : 0.f;
    fcw1[T].u[0] = cvtpk(cv[0], cv[1]); fcw1[T].u[1] = cvtpk(cv[2], cv[3]);
    fcw1[T].u[2] = cvtpk(cv[4], cv[5]); fcw1[T].u[3] = cvtpk(cv[6], cv[7]);
  }
  float cb2v = cb2[0];
  __syncthreads();

  // ---- per-lane constants from LDS ----
  f32x4 eb2r;
#pragma unroll
  for (int r = 0; r < 4; ++r) eb2r[r] = sEB2[4 * g + r];
  float tw0[4], tw1[4];
#pragma unroll
  for (int r = 0; r < 4; ++r) {
    tw0[r] = sEW2p[256 * 17 + 4 * g + r];
    tw1[r] = sEW2p[257 * 17 + 4 * g + r];
  }
  float a256 = sA[256], a257 = sA[257], w356 = sW3[256], w357 = sW3[257];

  const f32x2* sA2 = (const f32x2*)sA;
  const f32x2* sW32 = (const f32x2*)sW3;
  const char* Bbyte = (const char*)Bb;
  const int ewb = g * 136 + r16;           // sEW2p dword base for this lane

  float macc[4] = {0.f, 0.f, 0.f, 0.f};
  float cax = 0.f, cay = 0.f, caz = 0.f;

#pragma unroll 1
  for (int p = 0; p < 2; ++p) {
    const int jb = wv * 16 + p * 512;
    float djp[8];
    f32x4 D[8];
    const char* brow[8];
#pragma unroll
    for (int tt = 0; tt < 8; ++tt) {
      djp[tt] = sRel4[jb + tt * 64 + r16].w;
      D[tt] = eb2r;
      brow[tt] = Bbyte + (size_t)((jb + tt * 64 + r16) * (EHP * 2) + g * 16);
    }

    // ---- k-loop: 8 steps, double-buffered B-tile prefetch ----
    u32x4 bqA[8], bqB[8];
#pragma unroll
    for (int tt = 0; tt < 8; ++tt) bqA[tt] = *(const u32x4*)(brow[tt]);
#pragma unroll 1
    for (int sp = 0; sp < 4; ++sp) {
      const int s0i = 2 * sp, s1i = 2 * sp + 1;
#pragma unroll
      for (int tt = 0; tt < 8; ++tt) bqB[tt] = *(const u32x4*)(brow[tt] + s1i * 64);
      egc_step(s0i, bqA, djp, D, sA2, sW32, sEW2p, ewb, g);
      if (sp < 3) {
#pragma unroll
        for (int tt = 0; tt < 8; ++tt) bqA[tt] = *(const u32x4*)(brow[tt] + (s1i + 1) * 64);
      }
      egc_step(s1i, bqB, djp, D, sA2, sW32, sEW2p, ewb, g);
    }

    // ---- per-tile tail (k=256,257) + coors MLP + accumulation ----
    const f32x4* cb14 = (const f32x4*)sCB1;
    const f32x4* cw24 = (const f32x4*)sCW2;
#pragma unroll
    for (int tt = 0; tt < 8; ++tt) {
      const int j = jb + tt * 64 + r16;
      float4 rl = sRel4[j];
      uint32_t bt = *(const uint32_t*)(Bbyte + (size_t)(j * (EHP * 2) + 512));
      float h6 = fmaxf(fmaf(rl.w, w356, a256 + bflo(bt)), 0.f);
      float h7 = fmaxf(fmaf(rl.w, w357, a257 + bfhi(bt)), 0.f);
#pragma unroll
      for (int r = 0; r < 4; ++r) {
        D[tt][r] = fmaf(h6, tw0[r], D[tt][r]);
        D[tt][r] = fmaf(h7, tw1[r], D[tt][r]);
        macc[r] += D[tt][r];
      }
      // redistribute m^T D-frag -> B-frag (K padded to 32, zeros for k>=16)
      uint32_t p0 = cvtpk(D[tt][0], D[tt][1]);
      uint32_t p1 = cvtpk(D[tt][2], D[tt][3]);
      int s0 = r16 + (((2 * g) & 3) << 4);
      int s1 = r16 + (((2 * g + 1) & 3) << 4);
      uint32_t b0 = (uint32_t)__shfl((int)p0, s0, 64);
      uint32_t b1 = (uint32_t)__shfl((int)p1, s0, 64);
      uint32_t b2 = (uint32_t)__shfl((int)p0, s1, 64);
      uint32_t b3 = (uint32_t)__shfl((int)p1, s1, 64);
      B8 mf;
      mf.u[0] = (g < 2) ? b0 : 0u; mf.u[1] = (g < 2) ? b1 : 0u;
      mf.u[2] = (g < 2) ? b2 : 0u; mf.u[3] = (g < 2) ? b3 : 0u;
      float wacc = 0.f;
#pragma unroll
      for (int T = 0; T < 4; ++T) {
        f32x4 cbv = cb14[4 * T + g];
        f32x4 hd = __builtin_amdgcn_mfma_f32_16x16x32_bf16(fcw1[T].v, mf.v, cbv, 0, 0, 0);
        f32x4 cwv = cw24[4 * T + g];
#pragma unroll
        for (int r = 0; r < 4; ++r)
          wacc = fmaf(fmaxf(hd[r], 0.f), cwv[r], wacc);
      }
      wacc += __shfl_xor(wacc, 16, 64);
      wacc += __shfl_xor(wacc, 32, 64);
      float w = cb2v + wacc;
      cax = fmaf(w, rl.x, cax); cay = fmaf(w, rl.y, cay); caz = fmaf(w, rl.z, caz);
    }
  }

  // ---- reductions: sum over r16 (j within wave) ----
#pragma unroll
  for (int off = 1; off < 16; off <<= 1) {
#pragma unroll
    for (int r = 0; r < 4; ++r) macc[r] += __shfl_xor(macc[r], off, 64);
    cax += __shfl_xor(cax, off, 64);
    cay += __shfl_xor(cay, off, 64);
    caz += __shfl_xor(caz, off, 64);
  }
  if (r16 == 0) {
#pragma unroll
    for (int r = 0; r < 4; ++r) sE.redm[wv][4 * g + r] = macc[r];
    if (g == 0) { sE.redc[wv][0] = cax; sE.redc[wv][1] = cay; sE.redc[wv][2] = caz; }
  }
  __syncthreads();
  if (t < MDIM)
    sE.mi[t] = sE.redm[0][t] + sE.redm[1][t] + sE.redm[2][t] + sE.redm[3][t];
  if (t >= 16 && t < 19) {
    int c = t - 16;
    out[N * DIM + i * 3 + c] = sE.redc[0][c] + sE.redc[1][c] + sE.redc[2][c] + sE.redc[3][c];
  }
  __syncthreads();

  // ---- hidden mlp: [feats(64), m_i(16)] -> 128 -> relu -> 64 ----
  if (t < HH) {
    float acc = hb1[t];
#pragma unroll 8
    for (int d = 0; d < DIM; ++d) acc = fmaf(sFeat[d], hW1[d * HH + t], acc);
#pragma unroll
    for (int d = 0; d < MDIM; ++d) acc = fmaf(sE.mi[d], hW1[(DIM + d) * HH + t], acc);
    sE.hid[t] = fmaxf(acc, 0.f);
  }
  __syncthreads();
  if (t < DIM) {
    float acc = hb2[t];
#pragma unroll 8
    for (int c = 0; c < HH; ++c) acc = fmaf(sE.hid[c], hW2[c * DIM + t], acc);
    out[i * DIM + t] = acc;
  }
}

extern "C" void kernel_launch(void* const* d_in, const int* in_sizes, int n_in,
                              void* d_out, int out_size, void* d_ws, size_t ws_size,
                              hipStream_t stream) {
  const float* feats = (const float*)d_in[0];
  const float* coors = (const float*)d_in[1];
  const float* eW1   = (const float*)d_in[2];
  const float* eb1   = (const float*)d_in[3];
  const float* eW2   = (const float*)d_in[4];
  const float* eb2   = (const float*)d_in[5];
  const float* cW1   = (const float*)d_in[6];
  const float* cb1   = (const float*)d_in[7];
  const float* cW2   = (const float*)d_in[8];
  const float* cb2   = (const float*)d_in[9];
  const float* hW1   = (const float*)d_in[10];
  const float* hb1   = (const float*)d_in[11];
  const float* hW2   = (const float*)d_in[12];
  const float* hb2   = (const float*)d_in[13];

  float* A = (float*)d_ws;                                     // 1024*258 f32
  __hip_bfloat16* Bb = (__hip_bfloat16*)((char*)d_ws + (size_t)N * EH * 4);  // 1024*264 bf16
  float* out = (float*)d_out;

  eg_pre<<<N / PRE_ROWS, 256, 0, stream>>>(feats, eW1, eb1, A, Bb);
  eg_main<<<N, 256, 0, stream>>>(feats, coors, eW1, eW2, eb2, cW1, cb1, cW2, cb2,
                                 hW1, hb1, hW2, hb2, A, Bb, out);
}

// Round 9
// 164.042 us; speedup vs baseline: 1.2644x; 1.0138x over previous
//
#include <hip/hip_runtime.h>
#include <hip/hip_bf16.h>
#include <stdint.h>

#define N 1024
#define DIM 64
#define MDIM 16
#define EH 258    // edge mlp hidden
#define EHP 264   // padded Bb row stride (elements); 528 bytes
#define CH 64
#define HH 128
#define PRE_ROWS 8

typedef __bf16 bf16x8 __attribute__((ext_vector_type(8)));
typedef float f32x4 __attribute__((ext_vector_type(4)));
typedef float f32x2 __attribute__((ext_vector_type(2)));
typedef uint32_t u32x4 __attribute__((ext_vector_type(4)));
union B8 { uint32_t u[4]; bf16x8 v; };

__device__ __forceinline__ uint32_t cvtpk(float lo, float hi) {
  uint32_t r;
  asm("v_cvt_pk_bf16_f32 %0, %1, %2" : "=v"(r) : "v"(lo), "v"(hi));
  return r;
}
__device__ __forceinline__ f32x2 pk_add(f32x2 a, f32x2 b) {
  f32x2 r;
  asm("v_pk_add_f32 %0, %1, %2" : "=v"(r) : "v"(a), "v"(b));
  return r;
}
__device__ __forceinline__ f32x2 pk_fma(f32x2 a, f32x2 b, f32x2 c) {
  f32x2 r;
  asm("v_pk_fma_f32 %0, %1, %2, %3" : "=v"(r) : "v"(a), "v"(b), "v"(c));
  return r;
}
__device__ __forceinline__ float bflo(uint32_t u) { return __uint_as_float(u << 16); }
__device__ __forceinline__ float bfhi(uint32_t u) { return __uint_as_float(u & 0xffff0000u); }

// A[i][k] = feats[i] @ eW1[0:64,k] + eb1[k]   (f32, stride EH)
// Bb[j][k] = feats[j] @ eW1[64:128,k]         (bf16, row-major, stride EHP)
__global__ __launch_bounds__(256) void eg_pre(
    const float* __restrict__ feats, const float* __restrict__ eW1,
    const float* __restrict__ eb1,
    float* __restrict__ A, __hip_bfloat16* __restrict__ Bb)
{
  __shared__ float sf[PRE_ROWS][DIM];
  int ib = blockIdx.x, t = threadIdx.x;
  for (int q = t; q < PRE_ROWS * DIM; q += 256)
    sf[q >> 6][q & 63] = feats[ib * PRE_ROWS * DIM + q];
  __syncthreads();
  for (int k = t; k < EH; k += 256) {
    float bias = eb1[k];
    float a[PRE_ROWS], bv[PRE_ROWS];
#pragma unroll
    for (int ii = 0; ii < PRE_ROWS; ++ii) { a[ii] = bias; bv[ii] = 0.f; }
#pragma unroll 4
    for (int d = 0; d < DIM; ++d) {
      float wt = eW1[d * EH + k];
      float wb = eW1[(DIM + d) * EH + k];
#pragma unroll
      for (int ii = 0; ii < PRE_ROWS; ++ii) {
        a[ii]  = fmaf(sf[ii][d], wt, a[ii]);
        bv[ii] = fmaf(sf[ii][d], wb, bv[ii]);
      }
    }
#pragma unroll
    for (int ii = 0; ii < PRE_ROWS; ++ii) {
      A[(ib * PRE_ROWS + ii) * EH + k] = a[ii];
      Bb[(ib * PRE_ROWS + ii) * EHP + k] = __float2bfloat16(bv[ii]);
    }
  }
}

__global__ __launch_bounds__(256, 2) void eg_main(
    const float* __restrict__ feats, const float* __restrict__ coors,
    const float* __restrict__ eW1, const float* __restrict__ eW2,
    const float* __restrict__ eb2, const float* __restrict__ cW1,
    const float* __restrict__ cb1, const float* __restrict__ cW2,
    const float* __restrict__ cb2, const float* __restrict__ hW1,
    const float* __restrict__ hb1, const float* __restrict__ hW2,
    const float* __restrict__ hb2,
    const float* __restrict__ A, const __hip_bfloat16* __restrict__ Bb,
    float* __restrict__ out)
{
  __shared__ __align__(16) float sA[EHP];
  __shared__ __align__(16) float sW3[EHP];
  __shared__ __align__(16) float4 sRel4[N];         // {rx,ry,rz,dist}  16 KB
  __shared__ __align__(16) float sCB1[CH];
  __shared__ __align__(16) float sCW2[CH];
  __shared__ float sEB2[MDIM], sFeat[DIM];
  __shared__ struct { float redm[4][16]; float redc[4][3]; float mi[MDIM]; float hid[HH]; } sE;

  const int i = blockIdx.x, t = threadIdx.x;
  const int lane = t & 63, wv = t >> 6;
  const int r16 = lane & 15, g = lane >> 4;

  // ---- cooperative LDS staging ----
  for (int q = t; q < EH; q += 256) { sA[q] = A[i * EH + q]; sW3[q] = eW1[128 * EH + q]; }
  if (t < CH)   { sCB1[t] = cb1[t]; sCW2[t] = cW2[t]; }
  if (t < MDIM) sEB2[t] = eb2[t];
  if (t < DIM)  sFeat[t] = feats[i * DIM + t];
  {
    float cx = coors[i * 3], cy = coors[i * 3 + 1], cz = coors[i * 3 + 2];
    const float4* c4 = (const float4*)coors;
    float4 ca = c4[t * 3 + 0], cb = c4[t * 3 + 1], cc = c4[t * 3 + 2];
    float jx[4] = {ca.x, ca.w, cb.z, cc.y};
    float jy[4] = {ca.y, cb.x, cb.w, cc.z};
    float jz[4] = {ca.z, cb.y, cc.x, cc.w};
#pragma unroll
    for (int q = 0; q < 4; ++q) {
      float rx = cx - jx[q], ry = cy - jy[q], rz = cz - jz[q];
      float d = sqrtf(fmaf(rx, rx, fmaf(ry, ry, rz * rz)));
      sRel4[t * 4 + q] = make_float4(rx, ry, rz, d);
    }
  }

  // ---- one-time register gathers from global (L1/L2-hot, no LDS round-trip) ----
  // eW2^T A-fragments for all 8 k-steps: few[s] covers k = s*32 + g*8 .. +7
  B8 few[8];
#pragma unroll
  for (int s = 0; s < 8; ++s) {
    const float* ew = eW2 + (s * 32 + g * 8) * MDIM + r16;
    float fe[8];
#pragma unroll
    for (int e = 0; e < 8; ++e) fe[e] = ew[e * MDIM];
    few[s].u[0] = cvtpk(fe[0], fe[1]); few[s].u[1] = cvtpk(fe[2], fe[3]);
    few[s].u[2] = cvtpk(fe[4], fe[5]); few[s].u[3] = cvtpk(fe[6], fe[7]);
  }
  // cW1^T A-fragments (K padded 16->32: groups g>=2 are zero)
  B8 fcw1[4];
#pragma unroll
  for (int T = 0; T < 4; ++T) {
    float cv[8];
#pragma unroll
    for (int e = 0; e < 8; ++e)
      cv[e] = (g < 2) ? cW1[(8 * g + e) * CH + 16 * T + r16] : 0.f;
    fcw1[T].u[0] = cvtpk(cv[0], cv[1]); fcw1[T].u[1] = cvtpk(cv[2], cv[3]);
    fcw1[T].u[2] = cvtpk(cv[4], cv[5]); fcw1[T].u[3] = cvtpk(cv[6], cv[7]);
  }
  // tail (k=256,257) eW2 rows
  float tw0[4], tw1[4];
#pragma unroll
  for (int r = 0; r < 4; ++r) {
    tw0[r] = eW2[256 * MDIM + 4 * g + r];
    tw1[r] = eW2[257 * MDIM + 4 * g + r];
  }
  float cb2v = cb2[0];
  __syncthreads();

  // ---- per-lane constants from LDS ----
  f32x4 eb2r;
#pragma unroll
  for (int r = 0; r < 4; ++r) eb2r[r] = sEB2[4 * g + r];
  float a256 = sA[256], a257 = sA[257], w356 = sW3[256], w357 = sW3[257];

  const f32x2* sA2 = (const f32x2*)sA;
  const f32x2* sW32 = (const f32x2*)sW3;
  const char* Bbyte = (const char*)Bb;

  float macc[4] = {0.f, 0.f, 0.f, 0.f};
  float cax = 0.f, cay = 0.f, caz = 0.f;

#pragma unroll 1
  for (int p = 0; p < 2; ++p) {
    const int jb = wv * 16 + p * 512;
    float djp[8];
    f32x4 D[8];
    const char* brow[8];
#pragma unroll
    for (int tt = 0; tt < 8; ++tt) {
      djp[tt] = sRel4[jb + tt * 64 + r16].w;
      D[tt] = eb2r;
      brow[tt] = Bbyte + (size_t)((jb + tt * 64 + r16) * (EHP * 2) + g * 16);
    }

    // ---- k-loop: compiler-scheduled (round-5 form), few in registers ----
#pragma unroll
    for (int s = 0; s < 8; ++s) {
      f32x2 a2[4], w2[4];
#pragma unroll
      for (int q = 0; q < 4; ++q) {
        a2[q] = sA2[16 * s + 4 * g + q];
        w2[q] = sW32[16 * s + 4 * g + q];
      }
#pragma unroll
      for (int tt = 0; tt < 8; ++tt) {
        u32x4 bq = *(const u32x4*)(brow[tt] + s * 64);
        f32x2 dd; dd[0] = djp[tt]; dd[1] = djp[tt];
        B8 hb;
#pragma unroll
        for (int q = 0; q < 4; ++q) {
          f32x2 bp; bp[0] = bflo(bq[q]); bp[1] = bfhi(bq[q]);
          f32x2 hv = pk_add(bp, a2[q]);
          hv = pk_fma(dd, w2[q], hv);
          hb.u[q] = cvtpk(fmaxf(hv[0], 0.f), fmaxf(hv[1], 0.f));
        }
        D[tt] = __builtin_amdgcn_mfma_f32_16x16x32_bf16(few[s].v, hb.v, D[tt], 0, 0, 0);
      }
    }

    // ---- per-tile tail (k=256,257) + coors MLP + accumulation ----
    const f32x4* cb14 = (const f32x4*)sCB1;
    const f32x4* cw24 = (const f32x4*)sCW2;
#pragma unroll
    for (int tt = 0; tt < 8; ++tt) {
      const int j = jb + tt * 64 + r16;
      float4 rl = sRel4[j];
      uint32_t bt = *(const uint32_t*)(Bbyte + (size_t)(j * (EHP * 2) + 512));
      float h6 = fmaxf(fmaf(rl.w, w356, a256 + bflo(bt)), 0.f);
      float h7 = fmaxf(fmaf(rl.w, w357, a257 + bfhi(bt)), 0.f);
#pragma unroll
      for (int r = 0; r < 4; ++r) {
        D[tt][r] = fmaf(h6, tw0[r], D[tt][r]);
        D[tt][r] = fmaf(h7, tw1[r], D[tt][r]);
        macc[r] += D[tt][r];
      }
      // redistribute m^T D-frag -> B-frag (K padded to 32, zeros for k>=16)
      uint32_t p0 = cvtpk(D[tt][0], D[tt][1]);
      uint32_t p1 = cvtpk(D[tt][2], D[tt][3]);
      int s0 = r16 + (((2 * g) & 3) << 4);
      int s1 = r16 + (((2 * g + 1) & 3) << 4);
      uint32_t b0 = (uint32_t)__shfl((int)p0, s0, 64);
      uint32_t b1 = (uint32_t)__shfl((int)p1, s0, 64);
      uint32_t b2 = (uint32_t)__shfl((int)p0, s1, 64);
      uint32_t b3 = (uint32_t)__shfl((int)p1, s1, 64);
      B8 mf;
      mf.u[0] = (g < 2) ? b0 : 0u; mf.u[1] = (g < 2) ? b1 : 0u;
      mf.u[2] = (g < 2) ? b2 : 0u; mf.u[3] = (g < 2) ? b3 : 0u;
      float wacc = 0.f;
#pragma unroll
      for (int T = 0; T < 4; ++T) {
        f32x4 cbv = cb14[4 * T + g];
        f32x4 hd = __builtin_amdgcn_mfma_f32_16x16x32_bf16(fcw1[T].v, mf.v, cbv, 0, 0, 0);
        f32x4 cwv = cw24[4 * T + g];
#pragma unroll
        for (int r = 0; r < 4; ++r)
          wacc = fmaf(fmaxf(hd[r], 0.f), cwv[r], wacc);
      }
      wacc += __shfl_xor(wacc, 16, 64);
      wacc += __shfl_xor(wacc, 32, 64);
      float w = cb2v + wacc;
      cax = fmaf(w, rl.x, cax); cay = fmaf(w, rl.y, cay); caz = fmaf(w, rl.z, caz);
    }
  }

  // ---- reductions: sum over r16 (j within wave) ----
#pragma unroll
  for (int off = 1; off < 16; off <<= 1) {
#pragma unroll
    for (int r = 0; r < 4; ++r) macc[r] += __shfl_xor(macc[r], off, 64);
    cax += __shfl_xor(cax, off, 64);
    cay += __shfl_xor(cay, off, 64);
    caz += __shfl_xor(caz, off, 64);
  }
  if (r16 == 0) {
#pragma unroll
    for (int r = 0; r < 4; ++r) sE.redm[wv][4 * g + r] = macc[r];
    if (g == 0) { sE.redc[wv][0] = cax; sE.redc[wv][1] = cay; sE.redc[wv][2] = caz; }
  }
  __syncthreads();
  if (t < MDIM)
    sE.mi[t] = sE.redm[0][t] + sE.redm[1][t] + sE.redm[2][t] + sE.redm[3][t];
  if (t >= 16 && t < 19) {
    int c = t - 16;
    out[N * DIM + i * 3 + c] = sE.redc[0][c] + sE.redc[1][c] + sE.redc[2][c] + sE.redc[3][c];
  }
  __syncthreads();

  // ---- hidden mlp: [feats(64), m_i(16)] -> 128 -> relu -> 64 ----
  if (t < HH) {
    float acc = hb1[t];
#pragma unroll 8
    for (int d = 0; d < DIM; ++d) acc = fmaf(sFeat[d], hW1[d * HH + t], acc);
#pragma unroll
    for (int d = 0; d < MDIM; ++d) acc = fmaf(sE.mi[d], hW1[(DIM + d) * HH + t], acc);
    sE.hid[t] = fmaxf(acc, 0.f);
  }
  __syncthreads();
  if (t < DIM) {
    float acc = hb2[t];
#pragma unroll 8
    for (int c = 0; c < HH; ++c) acc = fmaf(sE.hid[c], hW2[c * DIM + t], acc);
    out[i * DIM + t] = acc;
  }
}

extern "C" void kernel_launch(void* const* d_in, const int* in_sizes, int n_in,
                              void* d_out, int out_size, void* d_ws, size_t ws_size,
                              hipStream_t stream) {
  const float* feats = (const float*)d_in[0];
  const float* coors = (const float*)d_in[1];
  const float* eW1   = (const float*)d_in[2];
  const float* eb1   = (const float*)d_in[3];
  const float* eW2   = (const float*)d_in[4];
  const float* eb2   = (const float*)d_in[5];
  const float* cW1   = (const float*)d_in[6];
  const float* cb1   = (const float*)d_in[7];
  const float* cW2   = (const float*)d_in[8];
  const float* cb2   = (const float*)d_in[9];
  const float* hW1   = (const float*)d_in[10];
  const float* hb1   = (const float*)d_in[11];
  const float* hW2   = (const float*)d_in[12];
  const float* hb2   = (const float*)d_in[13];

  float* A = (float*)d_ws;                                     // 1024*258 f32
  __hip_bfloat16* Bb = (__hip_bfloat16*)((char*)d_ws + (size_t)N * EH * 4);  // 1024*264 bf16
  float* out = (float*)d_out;

  eg_pre<<<N / PRE_ROWS, 256, 0, stream>>>(feats, eW1, eb1, A, Bb);
  eg_main<<<N, 256, 0, stream>>>(feats, coors, eW1, eW2, eb2, cW1, cb1, cW2, cb2,
                                 hW1, hb1, hW2, hb2, A, Bb, out);
}